// Round 4
// baseline (105.527 us; speedup 1.0000x reference)
//
#include <hip/hip_runtime.h>
#include <math.h>

#define NHEAD 8
#define NPT 4
#define HDIM 32
#define IMG 64      // H = W = 64
#define CDIM 256
#define NQ 4096
#define BATCH 8
#define MTOT (BATCH * NQ)   // 32768

typedef __attribute__((ext_vector_type(8))) short bf16x8;
typedef __attribute__((ext_vector_type(4))) float f32x4;

__device__ __forceinline__ unsigned short f2b(float f) {
    union { float f; unsigned u; } v; v.f = f;
    unsigned r = (v.u + 0x7FFFu + ((v.u >> 16) & 1u)) >> 16;
    return (unsigned short)r;
}
__device__ __forceinline__ float b2f(unsigned short u) {
    union { unsigned u; float f; } v; v.u = ((unsigned)u) << 16;
    return v.f;
}

// XOR swizzle: spreads rows across banks for ds_read_b128 column-slice reads.
#define SWZ(row, col) ((col) ^ (((row) & 7) << 3))

// ---------------------------------------------------------------------------
// Weight prep:
//  - Wv_t / Wo_t: [n][k] bf16 transposed copies of W_val / W_out
//  - Wl_h / Wl_l: [128][256] bf16 hi/lo split of packed [W_off | W_attn | 0pad]
//  - bias_lin[128]: b_off | b_attn | 0
// ---------------------------------------------------------------------------
__global__ __launch_bounds__(256)
void cvt_weights_kernel(const float* __restrict__ Wv, const float* __restrict__ Wo,
                        const float* __restrict__ Woff, const float* __restrict__ Wattn,
                        const float* __restrict__ boff, const float* __restrict__ battn,
                        unsigned short* __restrict__ Wv_t, unsigned short* __restrict__ Wo_t,
                        unsigned short* __restrict__ Wl_h, unsigned short* __restrict__ Wl_l,
                        float* __restrict__ bias_lin)
{
    int tid = blockIdx.x * 256 + threadIdx.x;   // 0 .. 65535
    int n = tid & 255, k = tid >> 8;
    Wv_t[n * 256 + k] = f2b(Wv[k * 256 + n]);
    Wo_t[n * 256 + k] = f2b(Wo[k * 256 + n]);
    if (tid < 128 * 256) {
        int nn = tid >> 8;       // output col 0..127
        int kk = tid & 255;
        float v = (nn < 64) ? Woff[kk * 64 + nn]
                : (nn < 96) ? Wattn[kk * 32 + (nn - 64)] : 0.f;
        unsigned short hi = f2b(v);
        unsigned short lo = f2b(v - b2f(hi));
        Wl_h[nn * 256 + kk] = hi;
        Wl_l[nn * 256 + kk] = lo;
    }
    if (tid < 128)
        bias_lin[tid] = (tid < 64) ? boff[tid] : (tid < 96) ? battn[tid - 64] : 0.f;
}

// ---------------------------------------------------------------------------
// Fused: split-precision MFMA logits -> tanh/softmax epilogue (in LDS) ->
// wave-autonomous bilinear gather. Block = 128 queries, 4 waves.
// ---------------------------------------------------------------------------
__global__ __launch_bounds__(256)
void fused_lin_sample_kernel(const float* __restrict__ Q,
                             const unsigned short* __restrict__ Wl_h,
                             const unsigned short* __restrict__ Wl_l,
                             const float* __restrict__ bias,
                             const float* __restrict__ refp,
                             const unsigned short* __restrict__ projv,
                             unsigned short* __restrict__ sampled)
{
    __shared__ char smem[65536];              // union: staging | results
    __shared__ float s_ref[256];              // 128 queries x (x,y)
    __shared__ float s_wxy[4][2][32][5];      // per-wave scratch: w4 + xy

    unsigned short (*Ah)[64] = (unsigned short(*)[64])(smem);
    unsigned short (*Al)[64] = (unsigned short(*)[64])(smem + 16384);
    unsigned short (*Bh)[64] = (unsigned short(*)[64])(smem + 32768);
    unsigned short (*Bl)[64] = (unsigned short(*)[64])(smem + 49152);
    float (*s_off)[64] = (float(*)[64])(smem);            // 32KB (tanh*0.5 applied)
    float (*s_aw)[32]  = (float(*)[32])(smem + 32768);    // 16KB (softmax weights)

    const int tid  = threadIdx.x;
    const int lane = tid & 63;
    const int wid  = tid >> 6;
    const int gm = blockIdx.x * 128;
    const int wr = (wid >> 1) * 64;
    const int wc = (wid & 1) * 64;
    const int l15 = lane & 15;
    const int lk  = (lane >> 4) * 8;

    // refp for this block's 128 queries
    s_ref[tid] = refp[(size_t)gm * 2 + tid];

    f32x4 acc[4][4];
    #pragma unroll
    for (int m = 0; m < 4; ++m)
        #pragma unroll
        for (int n = 0; n < 4; ++n)
            #pragma unroll
            for (int r = 0; r < 4; ++r) acc[m][n][r] = 0.f;

    // ---- Phase 1: split-precision MFMA for logits ----
    for (int k0 = 0; k0 < 256; k0 += 64) {
        __syncthreads();   // also covers first-iteration s_ref visibility
        #pragma unroll
        for (int it = 0; it < 4; ++it) {
            const int chunk = it * 256 + tid;
            const int row = chunk >> 3;
            const int kc  = (chunk & 7) << 3;
            const float4* src = (const float4*)&Q[(size_t)(gm + row) * 256 + k0 + kc];
            const float4 a = src[0], b = src[1];
            float f[8] = {a.x, a.y, a.z, a.w, b.x, b.y, b.z, b.w};
            unsigned short h[8], l[8];
            #pragma unroll
            for (int j = 0; j < 8; ++j) {
                h[j] = f2b(f[j]);
                l[j] = f2b(f[j] - b2f(h[j]));
            }
            const int sc = SWZ(row, kc);
            *(uint4*)&Ah[row][sc] = *(const uint4*)h;
            *(uint4*)&Al[row][sc] = *(const uint4*)l;
            *(uint4*)&Bh[row][sc] = *(const uint4*)&Wl_h[(size_t)row * 256 + k0 + kc];
            *(uint4*)&Bl[row][sc] = *(const uint4*)&Wl_l[(size_t)row * 256 + k0 + kc];
        }
        __syncthreads();

        #pragma unroll
        for (int kk = 0; kk < 64; kk += 32) {
            bf16x8 ah[4], al[4], bh[4], bl[4];
            #pragma unroll
            for (int m = 0; m < 4; ++m) {
                const int r = wr + m * 16 + l15;
                const int c = SWZ(r, kk + lk);
                ah[m] = *(const bf16x8*)&Ah[r][c];
                al[m] = *(const bf16x8*)&Al[r][c];
            }
            #pragma unroll
            for (int n = 0; n < 4; ++n) {
                const int r = wc + n * 16 + l15;
                const int c = SWZ(r, kk + lk);
                bh[n] = *(const bf16x8*)&Bh[r][c];
                bl[n] = *(const bf16x8*)&Bl[r][c];
            }
            #pragma unroll
            for (int m = 0; m < 4; ++m)
                #pragma unroll
                for (int n = 0; n < 4; ++n) {
                    acc[m][n] = __builtin_amdgcn_mfma_f32_16x16x32_bf16(ah[m], bh[n], acc[m][n], 0, 0, 0);
                    acc[m][n] = __builtin_amdgcn_mfma_f32_16x16x32_bf16(ah[m], bl[n], acc[m][n], 0, 0, 0);
                    acc[m][n] = __builtin_amdgcn_mfma_f32_16x16x32_bf16(al[m], bh[n], acc[m][n], 0, 0, 0);
                }
        }
    }
    __syncthreads();   // all MFMA LDS reads done -> safe to overwrite staging

    // ---- Epilogue: offsets (tanh*0.5) or attn softmax, into LDS ----
    const int cr = (lane >> 4) * 4;
    if (wc == 0) {
        #pragma unroll
        for (int n = 0; n < 4; ++n) {
            const int col = n * 16 + l15;
            const float bv = bias[col];
            #pragma unroll
            for (int m = 0; m < 4; ++m)
                #pragma unroll
                for (int r = 0; r < 4; ++r) {
                    const int row = wr + m * 16 + cr + r;
                    s_off[row][col] = tanhf(acc[m][n][r] + bv) * 0.5f;
                }
        }
    } else {
        #pragma unroll
        for (int n = 0; n < 2; ++n) {        // cols 64..95 only
            const int col = n * 16 + l15;    // 0..31 == h*4+p
            const float bv = bias[64 + col];
            #pragma unroll
            for (int m = 0; m < 4; ++m)
                #pragma unroll
                for (int r = 0; r < 4; ++r) {
                    const int row = wr + m * 16 + cr + r;
                    float v = acc[m][n][r] + bv;
                    float mx = v;
                    mx = fmaxf(mx, __shfl_xor(mx, 1));
                    mx = fmaxf(mx, __shfl_xor(mx, 2));
                    float e = expf(v - mx);
                    float ssum = e;
                    ssum += __shfl_xor(ssum, 1);
                    ssum += __shfl_xor(ssum, 2);
                    s_aw[row][col] = e / ssum;
                }
        }
    }
    __syncthreads();

    // ---- Phase 2: wave-autonomous gather (wave owns 32 queries) ----
    const int b = blockIdx.x >> 5;                 // 32 blocks per batch
    const int h2 = lane >> 3;                      // head for gather
    const int cp = lane & 7;                       // channel pair
    const unsigned short* vbase = projv + ((size_t)b << 20) + h2 * HDIM + cp * 2;

    for (int qi = 0; qi < 32; qi += 2) {
        // weights for 2 queries: all 64 lanes (sub = lane>>5, l5 = lane&31)
        {
            const int sub = lane >> 5;
            const int l5 = lane & 31;
            const int h = l5 >> 2;
            const int p = l5 & 3;
            const int qloc = wid * 32 + qi + sub;
            const float rx = s_ref[qloc * 2 + 0];
            const float ry = s_ref[qloc * 2 + 1];
            const float ox = s_off[qloc][h * 8 + p * 2 + 0];
            const float oy = s_off[qloc][h * 8 + p * 2 + 1];
            const float aw = s_aw[qloc][l5];

            const float lx = fminf(fmaxf(rx + ox, 0.f), 1.f);
            const float ly = fminf(fmaxf(ry + oy, 0.f), 1.f);
            const float x = lx * (float)IMG - 0.5f;
            const float y = ly * (float)IMG - 0.5f;
            const float x0f = floorf(x), y0f = floorf(y);
            const int x0 = (int)x0f, y0 = (int)y0f;
            const float wx1 = x - x0f, wx0 = 1.f - wx1;
            const float wy1 = y - y0f, wy0 = 1.f - wy1;
            const bool vx0 = (x0 >= 0), vx1 = (x0 + 1 < IMG);
            const bool vy0 = (y0 >= 0), vy1 = (y0 + 1 < IMG);
            float* dst = &s_wxy[wid][sub][l5][0];
            dst[0] = (vx0 && vy0) ? wx0 * wy0 * aw : 0.f;
            dst[1] = (vx1 && vy0) ? wx1 * wy0 * aw : 0.f;
            dst[2] = (vx0 && vy1) ? wx0 * wy1 * aw : 0.f;
            dst[3] = (vx1 && vy1) ? wx1 * wy1 * aw : 0.f;
            const int x0c = min(max(x0, 0), IMG - 1), x1c = min(max(x0 + 1, 0), IMG - 1);
            const int y0c = min(max(y0, 0), IMG - 1), y1c = min(max(y0 + 1, 0), IMG - 1);
            const unsigned xy = (unsigned)x0c | ((unsigned)x1c << 8)
                              | ((unsigned)y0c << 16) | ((unsigned)y1c << 24);
            ((unsigned*)dst)[4] = xy;
        }
        asm volatile("s_waitcnt lgkmcnt(0)" ::: "memory");

        #pragma unroll
        for (int s = 0; s < 2; ++s) {
            const int qloc = wid * 32 + qi + s;
            float a0 = 0.f, a1 = 0.f, a2 = 0.f, a3 = 0.f;
            #pragma unroll
            for (int p = 0; p < 4; ++p) {
                const float* src = &s_wxy[wid][s][h2 * 4 + p][0];
                const float w0 = src[0], w1 = src[1], w2 = src[2], w3 = src[3];
                const unsigned xy = ((const unsigned*)src)[4];
                const int x0 = xy & 255, x1 = (xy >> 8) & 255;
                const int y0 = (xy >> 16) & 255, y1 = xy >> 24;
                const int p00 = ((y0 << 6) + x0) << 8;
                const int p01 = ((y0 << 6) + x1) << 8;
                const int p10 = ((y1 << 6) + x0) << 8;
                const int p11 = ((y1 << 6) + x1) << 8;
                const unsigned u00a = *(const unsigned*)&vbase[p00];
                const unsigned u00b = *(const unsigned*)&vbase[p00 + 16];
                const unsigned u01a = *(const unsigned*)&vbase[p01];
                const unsigned u01b = *(const unsigned*)&vbase[p01 + 16];
                const unsigned u10a = *(const unsigned*)&vbase[p10];
                const unsigned u10b = *(const unsigned*)&vbase[p10 + 16];
                const unsigned u11a = *(const unsigned*)&vbase[p11];
                const unsigned u11b = *(const unsigned*)&vbase[p11 + 16];
                a0 += w0 * b2f((unsigned short)(u00a & 0xffff)) + w1 * b2f((unsigned short)(u01a & 0xffff))
                    + w2 * b2f((unsigned short)(u10a & 0xffff)) + w3 * b2f((unsigned short)(u11a & 0xffff));
                a1 += w0 * b2f((unsigned short)(u00a >> 16)) + w1 * b2f((unsigned short)(u01a >> 16))
                    + w2 * b2f((unsigned short)(u10a >> 16)) + w3 * b2f((unsigned short)(u11a >> 16));
                a2 += w0 * b2f((unsigned short)(u00b & 0xffff)) + w1 * b2f((unsigned short)(u01b & 0xffff))
                    + w2 * b2f((unsigned short)(u10b & 0xffff)) + w3 * b2f((unsigned short)(u11b & 0xffff));
                a3 += w0 * b2f((unsigned short)(u00b >> 16)) + w1 * b2f((unsigned short)(u01b >> 16))
                    + w2 * b2f((unsigned short)(u10b >> 16)) + w3 * b2f((unsigned short)(u11b >> 16));
            }
            unsigned short* orow = sampled + (size_t)(gm + qloc) * 256 + h2 * HDIM + cp * 2;
            *(unsigned*)&orow[0]  = (unsigned)f2b(a0) | ((unsigned)f2b(a1) << 16);
            *(unsigned*)&orow[16] = (unsigned)f2b(a2) | ((unsigned)f2b(a3) << 16);
        }
    }
}

// ---------------------------------------------------------------------------
// bf16 MFMA GEMM: C[M x 256] = A[M x 256] @ Bt^T + bias
// A_F32: A is f32, converted to bf16 during LDS staging (fused cvt).
// ---------------------------------------------------------------------------
template<bool A_F32, bool OUT_BF16>
__global__ __launch_bounds__(256)
void gemm_bf16_kernel(const void* __restrict__ Ap,
                      const unsigned short* __restrict__ Bt,
                      const float* __restrict__ bias,
                      void* __restrict__ C)
{
    __shared__ unsigned short As[128][64];
    __shared__ unsigned short Bs[128][64];

    const int tid  = threadIdx.x;
    const int lane = tid & 63;
    const int wid  = tid >> 6;
    const int gm = blockIdx.x * 128;
    const int gn = blockIdx.y * 128;
    const int wr = (wid >> 1) * 64;
    const int wc = (wid & 1) * 64;
    const int l15 = lane & 15;
    const int lk  = (lane >> 4) * 8;

    f32x4 acc[4][4];
    #pragma unroll
    for (int m = 0; m < 4; ++m)
        #pragma unroll
        for (int n = 0; n < 4; ++n)
            #pragma unroll
            for (int r = 0; r < 4; ++r) acc[m][n][r] = 0.f;

    for (int k0 = 0; k0 < 256; k0 += 64) {
        #pragma unroll
        for (int it = 0; it < 4; ++it) {
            const int chunk = it * 256 + tid;
            const int row = chunk >> 3;
            const int kc  = (chunk & 7) << 3;
            const int sc = SWZ(row, kc);
            if (A_F32) {
                const float4* src = (const float4*)&((const float*)Ap)[(size_t)(gm + row) * 256 + k0 + kc];
                const float4 a = src[0], b = src[1];
                float f[8] = {a.x, a.y, a.z, a.w, b.x, b.y, b.z, b.w};
                unsigned short h[8];
                #pragma unroll
                for (int j = 0; j < 8; ++j) h[j] = f2b(f[j]);
                *(uint4*)&As[row][sc] = *(const uint4*)h;
            } else {
                *(uint4*)&As[row][sc] =
                    *(const uint4*)&((const unsigned short*)Ap)[(size_t)(gm + row) * 256 + k0 + kc];
            }
            *(uint4*)&Bs[row][sc] = *(const uint4*)&Bt[(size_t)(gn + row) * 256 + k0 + kc];
        }
        __syncthreads();

        #pragma unroll
        for (int kk = 0; kk < 64; kk += 32) {
            bf16x8 a[4], b[4];
            #pragma unroll
            for (int m = 0; m < 4; ++m) {
                const int r = wr + m * 16 + l15;
                a[m] = *(const bf16x8*)&As[r][SWZ(r, kk + lk)];
            }
            #pragma unroll
            for (int n = 0; n < 4; ++n) {
                const int r = wc + n * 16 + l15;
                b[n] = *(const bf16x8*)&Bs[r][SWZ(r, kk + lk)];
            }
            #pragma unroll
            for (int m = 0; m < 4; ++m)
                #pragma unroll
                for (int n = 0; n < 4; ++n)
                    acc[m][n] = __builtin_amdgcn_mfma_f32_16x16x32_bf16(a[m], b[n], acc[m][n], 0, 0, 0);
        }
        __syncthreads();
    }

    const int cr = (lane >> 4) * 4;
    #pragma unroll
    for (int n = 0; n < 4; ++n) {
        const int col = gn + wc + n * 16 + l15;
        const float bv = bias[col];
        #pragma unroll
        for (int m = 0; m < 4; ++m) {
            #pragma unroll
            for (int r = 0; r < 4; ++r) {
                const int row = gm + wr + m * 16 + cr + r;
                const float v = acc[m][n][r] + bv;
                if (OUT_BF16)
                    ((unsigned short*)C)[(size_t)row * 256 + col] = f2b(v);
                else
                    ((float*)C)[(size_t)row * 256 + col] = v;
            }
        }
    }
}

// ---------------------------------------------------------------------------
extern "C" void kernel_launch(void* const* d_in, const int* in_sizes, int n_in,
                              void* d_out, int out_size, void* d_ws, size_t ws_size,
                              hipStream_t stream)
{
    const float* query  = (const float*)d_in[0];
    const float* value  = (const float*)d_in[1];
    const float* refp   = (const float*)d_in[2];
    const float* W_off  = (const float*)d_in[3];
    const float* b_off  = (const float*)d_in[4];
    const float* W_attn = (const float*)d_in[5];
    const float* b_attn = (const float*)d_in[6];
    const float* W_val  = (const float*)d_in[7];
    const float* b_val  = (const float*)d_in[8];
    const float* W_out  = (const float*)d_in[9];
    const float* b_out  = (const float*)d_in[10];
    float* out = (float*)d_out;

    // workspace layout
    char* ws = (char*)d_ws;
    unsigned short* projv    = (unsigned short*)ws; ws += (size_t)MTOT * 256 * 2;
    unsigned short* sampled  = (unsigned short*)ws; ws += (size_t)MTOT * 256 * 2;
    unsigned short* Wv_t     = (unsigned short*)ws; ws += 256 * 256 * 2;
    unsigned short* Wo_t     = (unsigned short*)ws; ws += 256 * 256 * 2;
    unsigned short* Wl_h     = (unsigned short*)ws; ws += 128 * 256 * 2;
    unsigned short* Wl_l     = (unsigned short*)ws; ws += 128 * 256 * 2;
    float*          bias_lin = (float*)ws;          ws += 128 * 4;

    dim3 blk(256);

    // 1) weight prep
    cvt_weights_kernel<<<dim3(256), blk, 0, stream>>>(W_val, W_out, W_off, W_attn, b_off, b_attn,
                                                      Wv_t, Wo_t, Wl_h, Wl_l, bias_lin);

    // 2) value projection (fused f32->bf16 A-staging): projv = value @ W_val + b_val -> bf16
    gemm_bf16_kernel<true, true><<<dim3(MTOT / 128, 2), blk, 0, stream>>>(value, Wv_t, b_val, projv);

    // 3) fused logits + softmax/tanh + bilinear gather -> sampled (bf16)
    fused_lin_sample_kernel<<<dim3(MTOT / 128), blk, 0, stream>>>(
        query, Wl_h, Wl_l, bias_lin, refp, projv, sampled);

    // 4) output projection: out = sampled @ W_out + b_out -> f32
    gemm_bf16_kernel<false, false><<<dim3(MTOT / 128, 2), blk, 0, stream>>>(sampled, Wo_t, b_out, out);
}

// Round 5
// 72.044 us; speedup vs baseline: 1.4648x; 1.4648x over previous
//
#include <hip/hip_runtime.h>
#include <math.h>

#define NHEAD 8
#define NPT 4
#define HDIM 32
#define IMG 64      // H = W = 64
#define CDIM 256
#define NQ 4096
#define BATCH 8
#define MTOT (BATCH * NQ)   // 32768

typedef __attribute__((ext_vector_type(8))) short bf16x8;
typedef __attribute__((ext_vector_type(4))) float f32x4;

__device__ __forceinline__ unsigned short f2b(float f) {
    union { float f; unsigned u; } v; v.f = f;
    unsigned r = (v.u + 0x7FFFu + ((v.u >> 16) & 1u)) >> 16;
    return (unsigned short)r;
}
__device__ __forceinline__ float b2f(unsigned short u) {
    union { unsigned u; float f; } v; v.u = ((unsigned)u) << 16;
    return v.f;
}

// XOR swizzle: spreads rows across banks for ds_read_b128 column-slice reads.
#define SWZ(row, col) ((col) ^ (((row) & 7) << 3))

// XCD pinning: batch = blockIdx.x & 7 lands on XCD (blockIdx % 8) round-robin.
// Each XCD then owns exactly one batch's projv/lin/sampled -> L2-resident.

// ---------------------------------------------------------------------------
// Weight prep:
//  - Wv_t / Wo_t: [n][k] bf16 transposed copies of W_val / W_out
//  - Wl_h / Wl_l: [128][256] bf16 hi/lo split of packed [W_off | W_attn | 0pad]
//  - bias_lin[128]: b_off | b_attn | 0
// ---------------------------------------------------------------------------
__global__ __launch_bounds__(256)
void cvt_weights_kernel(const float* __restrict__ Wv, const float* __restrict__ Wo,
                        const float* __restrict__ Woff, const float* __restrict__ Wattn,
                        const float* __restrict__ boff, const float* __restrict__ battn,
                        unsigned short* __restrict__ Wv_t, unsigned short* __restrict__ Wo_t,
                        unsigned short* __restrict__ Wl_h, unsigned short* __restrict__ Wl_l,
                        float* __restrict__ bias_lin)
{
    int tid = blockIdx.x * 256 + threadIdx.x;   // 0 .. 65535
    int n = tid & 255, k = tid >> 8;
    Wv_t[n * 256 + k] = f2b(Wv[k * 256 + n]);
    Wo_t[n * 256 + k] = f2b(Wo[k * 256 + n]);
    if (tid < 128 * 256) {
        int nn = tid >> 8;       // output col 0..127
        int kk = tid & 255;
        float v = (nn < 64) ? Woff[kk * 64 + nn]
                : (nn < 96) ? Wattn[kk * 32 + (nn - 64)] : 0.f;
        unsigned short hi = f2b(v);
        unsigned short lo = f2b(v - b2f(hi));
        Wl_h[nn * 256 + kk] = hi;
        Wl_l[nn * 256 + kk] = lo;
    }
    if (tid < 128)
        bias_lin[tid] = (tid < 64) ? boff[tid] : (tid < 96) ? battn[tid - 64] : 0.f;
}

// ---------------------------------------------------------------------------
// Split-precision MFMA GEMM for offset/attn logits:
//   lin[M x 96] = query(f32) @ [W_off|W_attn] + bias   via 3-term bf16 split
// 128x128 tile (cols 96..127 zero-pad skipped in compute), XCD-pinned rows.
// ---------------------------------------------------------------------------
__global__ __launch_bounds__(256)
void lin_gemm_kernel(const float* __restrict__ Q,
                     const unsigned short* __restrict__ Wl_h,
                     const unsigned short* __restrict__ Wl_l,
                     const float* __restrict__ bias,
                     float* __restrict__ lin)
{
    __shared__ unsigned short Ah[128][64], Al[128][64];
    __shared__ unsigned short Bh[128][64], Bl[128][64];

    const int tid  = threadIdx.x;
    const int lane = tid & 63;
    const int wid  = tid >> 6;
    const int gm = ((blockIdx.x & 7) << 12) + ((blockIdx.x >> 3) << 7);  // XCD-pinned
    const int wr = (wid >> 1) * 64;
    const int wc = (wid & 1) * 64;
    const int l15 = lane & 15;
    const int lk  = (lane >> 4) * 8;

    f32x4 acc[4][4];
    #pragma unroll
    for (int m = 0; m < 4; ++m)
        #pragma unroll
        for (int n = 0; n < 4; ++n)
            #pragma unroll
            for (int r = 0; r < 4; ++r) acc[m][n][r] = 0.f;

    for (int k0 = 0; k0 < 256; k0 += 64) {
        #pragma unroll
        for (int it = 0; it < 4; ++it) {
            const int chunk = it * 256 + tid;
            const int row = chunk >> 3;
            const int kc  = (chunk & 7) << 3;
            const float4* src = (const float4*)&Q[(size_t)(gm + row) * 256 + k0 + kc];
            const float4 a = src[0], b = src[1];
            float f[8] = {a.x, a.y, a.z, a.w, b.x, b.y, b.z, b.w};
            unsigned short h[8], l[8];
            #pragma unroll
            for (int j = 0; j < 8; ++j) {
                h[j] = f2b(f[j]);
                l[j] = f2b(f[j] - b2f(h[j]));
            }
            const int sc = SWZ(row, kc);
            *(uint4*)&Ah[row][sc] = *(const uint4*)h;
            *(uint4*)&Al[row][sc] = *(const uint4*)l;
            *(uint4*)&Bh[row][sc] = *(const uint4*)&Wl_h[(size_t)row * 256 + k0 + kc];
            *(uint4*)&Bl[row][sc] = *(const uint4*)&Wl_l[(size_t)row * 256 + k0 + kc];
        }
        __syncthreads();

        #pragma unroll
        for (int kk = 0; kk < 64; kk += 32) {
            bf16x8 ah[4], al[4];
            #pragma unroll
            for (int m = 0; m < 4; ++m) {
                const int r = wr + m * 16 + l15;
                const int c = SWZ(r, kk + lk);
                ah[m] = *(const bf16x8*)&Ah[r][c];
                al[m] = *(const bf16x8*)&Al[r][c];
            }
            if (wc == 0) {
                bf16x8 bh[4], bl[4];
                #pragma unroll
                for (int n = 0; n < 4; ++n) {
                    const int r = n * 16 + l15;
                    const int c = SWZ(r, kk + lk);
                    bh[n] = *(const bf16x8*)&Bh[r][c];
                    bl[n] = *(const bf16x8*)&Bl[r][c];
                }
                #pragma unroll
                for (int m = 0; m < 4; ++m)
                    #pragma unroll
                    for (int n = 0; n < 4; ++n) {
                        acc[m][n] = __builtin_amdgcn_mfma_f32_16x16x32_bf16(ah[m], bh[n], acc[m][n], 0, 0, 0);
                        acc[m][n] = __builtin_amdgcn_mfma_f32_16x16x32_bf16(ah[m], bl[n], acc[m][n], 0, 0, 0);
                        acc[m][n] = __builtin_amdgcn_mfma_f32_16x16x32_bf16(al[m], bh[n], acc[m][n], 0, 0, 0);
                    }
            } else {
                bf16x8 bh[2], bl[2];
                #pragma unroll
                for (int n = 0; n < 2; ++n) {
                    const int r = 64 + n * 16 + l15;
                    const int c = SWZ(r, kk + lk);
                    bh[n] = *(const bf16x8*)&Bh[r][c];
                    bl[n] = *(const bf16x8*)&Bl[r][c];
                }
                #pragma unroll
                for (int m = 0; m < 4; ++m)
                    #pragma unroll
                    for (int n = 0; n < 2; ++n) {
                        acc[m][n] = __builtin_amdgcn_mfma_f32_16x16x32_bf16(ah[m], bh[n], acc[m][n], 0, 0, 0);
                        acc[m][n] = __builtin_amdgcn_mfma_f32_16x16x32_bf16(ah[m], bl[n], acc[m][n], 0, 0, 0);
                        acc[m][n] = __builtin_amdgcn_mfma_f32_16x16x32_bf16(al[m], bh[n], acc[m][n], 0, 0, 0);
                    }
            }
        }
        __syncthreads();
    }

    const int cr = (lane >> 4) * 4;
    #pragma unroll
    for (int n = 0; n < 4; ++n) {
        const int col = wc + n * 16 + l15;
        if (col < 96) {
            const float bv = bias[col];
            #pragma unroll
            for (int m = 0; m < 4; ++m)
                #pragma unroll
                for (int r = 0; r < 4; ++r) {
                    const int row = gm + wr + m * 16 + cr + r;
                    lin[(size_t)row * 96 + col] = acc[m][n][r] + bv;
                }
        }
    }
}

// ---------------------------------------------------------------------------
// bf16 MFMA GEMM: C[M x 256] = A[M x 256] @ Bt^T + bias  (XCD-pinned rows)
// A_F32: A is f32, converted to bf16 during LDS staging (fused cvt).
// ---------------------------------------------------------------------------
template<bool A_F32, bool OUT_BF16>
__global__ __launch_bounds__(256)
void gemm_bf16_kernel(const void* __restrict__ Ap,
                      const unsigned short* __restrict__ Bt,
                      const float* __restrict__ bias,
                      void* __restrict__ C)
{
    __shared__ unsigned short As[128][64];
    __shared__ unsigned short Bs[128][64];

    const int tid  = threadIdx.x;
    const int lane = tid & 63;
    const int wid  = tid >> 6;
    const int gm = ((blockIdx.x & 7) << 12) + ((blockIdx.x >> 3) << 7);  // XCD-pinned
    const int gn = blockIdx.y * 128;
    const int wr = (wid >> 1) * 64;
    const int wc = (wid & 1) * 64;
    const int l15 = lane & 15;
    const int lk  = (lane >> 4) * 8;

    f32x4 acc[4][4];
    #pragma unroll
    for (int m = 0; m < 4; ++m)
        #pragma unroll
        for (int n = 0; n < 4; ++n)
            #pragma unroll
            for (int r = 0; r < 4; ++r) acc[m][n][r] = 0.f;

    for (int k0 = 0; k0 < 256; k0 += 64) {
        #pragma unroll
        for (int it = 0; it < 4; ++it) {
            const int chunk = it * 256 + tid;
            const int row = chunk >> 3;
            const int kc  = (chunk & 7) << 3;
            const int sc = SWZ(row, kc);
            if (A_F32) {
                const float4* src = (const float4*)&((const float*)Ap)[(size_t)(gm + row) * 256 + k0 + kc];
                const float4 a = src[0], b = src[1];
                float f[8] = {a.x, a.y, a.z, a.w, b.x, b.y, b.z, b.w};
                unsigned short h[8];
                #pragma unroll
                for (int j = 0; j < 8; ++j) h[j] = f2b(f[j]);
                *(uint4*)&As[row][sc] = *(const uint4*)h;
            } else {
                *(uint4*)&As[row][sc] =
                    *(const uint4*)&((const unsigned short*)Ap)[(size_t)(gm + row) * 256 + k0 + kc];
            }
            *(uint4*)&Bs[row][sc] = *(const uint4*)&Bt[(size_t)(gn + row) * 256 + k0 + kc];
        }
        __syncthreads();

        #pragma unroll
        for (int kk = 0; kk < 64; kk += 32) {
            bf16x8 a[4], b[4];
            #pragma unroll
            for (int m = 0; m < 4; ++m) {
                const int r = wr + m * 16 + l15;
                a[m] = *(const bf16x8*)&As[r][SWZ(r, kk + lk)];
            }
            #pragma unroll
            for (int n = 0; n < 4; ++n) {
                const int r = wc + n * 16 + l15;
                b[n] = *(const bf16x8*)&Bs[r][SWZ(r, kk + lk)];
            }
            #pragma unroll
            for (int m = 0; m < 4; ++m)
                #pragma unroll
                for (int n = 0; n < 4; ++n)
                    acc[m][n] = __builtin_amdgcn_mfma_f32_16x16x32_bf16(a[m], b[n], acc[m][n], 0, 0, 0);
        }
        __syncthreads();
    }

    const int cr = (lane >> 4) * 4;
    #pragma unroll
    for (int n = 0; n < 4; ++n) {
        const int col = gn + wc + n * 16 + l15;
        const float bv = bias[col];
        #pragma unroll
        for (int m = 0; m < 4; ++m) {
            #pragma unroll
            for (int r = 0; r < 4; ++r) {
                const int row = gm + wr + m * 16 + cr + r;
                const float v = acc[m][n][r] + bv;
                if (OUT_BF16)
                    ((unsigned short*)C)[(size_t)row * 256 + col] = f2b(v);
                else
                    ((float*)C)[(size_t)row * 256 + col] = v;
            }
        }
    }
}

// ---------------------------------------------------------------------------
// Sampling: block = 4 queries (XCD-pinned batch). 128 threads compute the
// 4x32 (h,p) corner weights/coords; then 256 threads gather: 64 lanes per
// query, 8 lanes x 8B per head slice, uint2 loads (4 bf16 channels/lane).
// ---------------------------------------------------------------------------
__global__ __launch_bounds__(256)
void sample_gather_kernel(const unsigned short* __restrict__ projv, // [B][4096][256] bf16
                          const float* __restrict__ lin,            // [M][96]
                          const float* __restrict__ refp,           // [M][2]
                          unsigned short* __restrict__ sampled)     // [M][256] bf16
{
    __shared__ float4 s_w[4][32];
    __shared__ unsigned s_xy[4][32];

    const int i = blockIdx.x;
    const int b = i & 7;                          // batch == XCD
    const int bn0 = (b << 12) + ((i >> 3) << 2);  // first of 4 queries
    const int t = threadIdx.x;

    if (t < 128) {
        const int sub = t >> 5;
        const int q = t & 31;          // h*4 + p
        const int h = q >> 2;
        const int p = q & 3;
        const int bn = bn0 + sub;
        const float2 rp = *(const float2*)&refp[(size_t)bn * 2];
        const float2 ol = *(const float2*)&lin[(size_t)bn * 96 + h * 8 + p * 2];
        const float al  = lin[(size_t)bn * 96 + 64 + q];

        float mx = al;
        mx = fmaxf(mx, __shfl_xor(mx, 1));
        mx = fmaxf(mx, __shfl_xor(mx, 2));
        float e = expf(al - mx);
        float s = e;
        s += __shfl_xor(s, 1);
        s += __shfl_xor(s, 2);
        const float aw = e / s;

        const float lx = fminf(fmaxf(rp.x + tanhf(ol.x) * 0.5f, 0.f), 1.f);
        const float ly = fminf(fmaxf(rp.y + tanhf(ol.y) * 0.5f, 0.f), 1.f);
        const float x = lx * (float)IMG - 0.5f;
        const float y = ly * (float)IMG - 0.5f;
        const float x0f = floorf(x), y0f = floorf(y);
        const int x0 = (int)x0f, y0 = (int)y0f;
        const float wx1 = x - x0f, wx0 = 1.f - wx1;
        const float wy1 = y - y0f, wy0 = 1.f - wy1;
        const bool vx0 = (x0 >= 0), vx1 = (x0 + 1 < IMG);
        const bool vy0 = (y0 >= 0), vy1 = (y0 + 1 < IMG);
        float4 w;
        w.x = (vx0 && vy0) ? wx0 * wy0 * aw : 0.f;
        w.y = (vx1 && vy0) ? wx1 * wy0 * aw : 0.f;
        w.z = (vx0 && vy1) ? wx0 * wy1 * aw : 0.f;
        w.w = (vx1 && vy1) ? wx1 * wy1 * aw : 0.f;
        const int x0c = min(max(x0, 0), IMG - 1), x1c = min(max(x0 + 1, 0), IMG - 1);
        const int y0c = min(max(y0, 0), IMG - 1), y1c = min(max(y0 + 1, 0), IMG - 1);
        s_w[sub][q] = w;
        s_xy[sub][q] = (unsigned)x0c | ((unsigned)x1c << 8) | ((unsigned)y0c << 16) | ((unsigned)y1c << 24);
    }
    __syncthreads();

    const int sub = t >> 6;
    const int l = t & 63;
    const int h2 = l >> 3;
    const int cp = l & 7;
    const int bn = bn0 + sub;
    const unsigned short* vbase = projv + ((size_t)b << 20) + h2 * HDIM + cp * 4;

    float a0 = 0.f, a1 = 0.f, a2 = 0.f, a3 = 0.f;
    #pragma unroll
    for (int p = 0; p < 4; ++p) {
        const float4 w = s_w[sub][h2 * 4 + p];
        const unsigned xy = s_xy[sub][h2 * 4 + p];
        const int x0 = xy & 255, x1 = (xy >> 8) & 255;
        const int y0 = (xy >> 16) & 255, y1 = xy >> 24;
        const uint2 u00 = *(const uint2*)&vbase[(((y0 << 6) + x0) << 8)];
        const uint2 u01 = *(const uint2*)&vbase[(((y0 << 6) + x1) << 8)];
        const uint2 u10 = *(const uint2*)&vbase[(((y1 << 6) + x0) << 8)];
        const uint2 u11 = *(const uint2*)&vbase[(((y1 << 6) + x1) << 8)];
        a0 += w.x * b2f((unsigned short)(u00.x & 0xffff)) + w.y * b2f((unsigned short)(u01.x & 0xffff))
            + w.z * b2f((unsigned short)(u10.x & 0xffff)) + w.w * b2f((unsigned short)(u11.x & 0xffff));
        a1 += w.x * b2f((unsigned short)(u00.x >> 16)) + w.y * b2f((unsigned short)(u01.x >> 16))
            + w.z * b2f((unsigned short)(u10.x >> 16)) + w.w * b2f((unsigned short)(u11.x >> 16));
        a2 += w.x * b2f((unsigned short)(u00.y & 0xffff)) + w.y * b2f((unsigned short)(u01.y & 0xffff))
            + w.z * b2f((unsigned short)(u10.y & 0xffff)) + w.w * b2f((unsigned short)(u11.y & 0xffff));
        a3 += w.x * b2f((unsigned short)(u00.y >> 16)) + w.y * b2f((unsigned short)(u01.y >> 16))
            + w.z * b2f((unsigned short)(u10.y >> 16)) + w.w * b2f((unsigned short)(u11.y >> 16));
    }
    uint2 outp;
    outp.x = (unsigned)f2b(a0) | ((unsigned)f2b(a1) << 16);
    outp.y = (unsigned)f2b(a2) | ((unsigned)f2b(a3) << 16);
    *(uint2*)&sampled[(size_t)bn * 256 + h2 * HDIM + cp * 4] = outp;
}

// ---------------------------------------------------------------------------
extern "C" void kernel_launch(void* const* d_in, const int* in_sizes, int n_in,
                              void* d_out, int out_size, void* d_ws, size_t ws_size,
                              hipStream_t stream)
{
    const float* query  = (const float*)d_in[0];
    const float* value  = (const float*)d_in[1];
    const float* refp   = (const float*)d_in[2];
    const float* W_off  = (const float*)d_in[3];
    const float* b_off  = (const float*)d_in[4];
    const float* W_attn = (const float*)d_in[5];
    const float* b_attn = (const float*)d_in[6];
    const float* W_val  = (const float*)d_in[7];
    const float* b_val  = (const float*)d_in[8];
    const float* W_out  = (const float*)d_in[9];
    const float* b_out  = (const float*)d_in[10];
    float* out = (float*)d_out;

    // workspace layout
    char* ws = (char*)d_ws;
    unsigned short* projv    = (unsigned short*)ws; ws += (size_t)MTOT * 256 * 2;
    unsigned short* sampled  = (unsigned short*)ws; ws += (size_t)MTOT * 256 * 2;
    float*          lin      = (float*)ws;          ws += (size_t)MTOT * 96 * 4;
    unsigned short* Wv_t     = (unsigned short*)ws; ws += 256 * 256 * 2;
    unsigned short* Wo_t     = (unsigned short*)ws; ws += 256 * 256 * 2;
    unsigned short* Wl_h     = (unsigned short*)ws; ws += 128 * 256 * 2;
    unsigned short* Wl_l     = (unsigned short*)ws; ws += 128 * 256 * 2;
    float*          bias_lin = (float*)ws;          ws += 128 * 4;

    dim3 blk(256);

    // 1) weight prep
    cvt_weights_kernel<<<dim3(256), blk, 0, stream>>>(W_val, W_out, W_off, W_attn, b_off, b_attn,
                                                      Wv_t, Wo_t, Wl_h, Wl_l, bias_lin);

    // 2) value projection (XCD-pinned): projv = value @ W_val + b_val -> bf16
    gemm_bf16_kernel<true, true><<<dim3(MTOT / 128, 2), blk, 0, stream>>>(value, Wv_t, b_val, projv);

    // 3) offset+attn logits via split-precision MFMA (XCD-pinned)
    lin_gemm_kernel<<<dim3(MTOT / 128), blk, 0, stream>>>(query, Wl_h, Wl_l, bias_lin, lin);

    // 4) sampling/gather (XCD-pinned batch -> L2-resident projv & lin)
    sample_gather_kernel<<<dim3(MTOT / 4), blk, 0, stream>>>(projv, lin, refp, sampled);

    // 5) output projection (XCD-pinned): out = sampled @ W_out + b_out -> f32
    gemm_bf16_kernel<false, false><<<dim3(MTOT / 128, 2), blk, 0, stream>>>(sampled, Wo_t, b_out, out);
}